// Round 8
// baseline (65.619 us; speedup 1.0000x reference)
//
#include <hip/hip_runtime.h>
#include <hip/hip_bf16.h>

// RSA layer, B=64, U=W=128. Grid 4x64 (256 blocks = 1/CU), 512 threads (8 waves).
// Only i=W-1 output row needed; hj-term and bias cancel in softmax over j.
// sim-hi matmul + dot matvec via bf16 MFMA 16x16x32; softmax with per-wave
// online (m,s,p) triples + ONE cross-wave exchange (2 barriers total).
// Staging: phase A issues ALL global loads into regs, phase B converts+writes.
constexpr int Bx = 64, Ux = 128, Wx = 128;
constexpr int NS = 4;           // v-chunks per batch
constexpr int VC = 32;          // v columns per block
constexpr int LDST = 136;       // st_s stride (bf16): 272B = 17*16B (b128-aligned rows)
constexpr int LDWT = 136;

typedef __attribute__((ext_vector_type(8))) short s16x8;   // MFMA A/B frag
typedef __attribute__((ext_vector_type(4))) float fx4;     // MFMA C/D frag

static __device__ __forceinline__ short f2b(float x) {     // f32 -> bf16 RNE (cvt_pk-able)
  __hip_bfloat16 h = __float2bfloat16(x);
  return *reinterpret_cast<short*>(&h);
}
static __device__ __forceinline__ float b2f(short s) {     // bf16 -> f32 exact
  union { unsigned u; float f; } c; c.u = ((unsigned)(unsigned short)s) << 16;
  return c.f;
}

__global__ __launch_bounds__(512) void rsa_kernel(const float* __restrict__ input,
                                                  const float* __restrict__ state,
                                                  const float* __restrict__ w,
                                                  float* __restrict__ out) {
  __shared__ __align__(16) short st_s[Wx][LDST];  // [j][k]=state[j][k], [j][128]=input[j]
  __shared__ __align__(16) short wst[VC][LDWT];   // [v][k]=w_hi[k-1][vb+v], [v][0]=0
  __shared__ float wm[8][VC], wsum[8][VC], wp[8][VC];  // per-wave (m,s,p) triples
  __shared__ float w127_s[VC], wdot_s[VC];
  __shared__ float dpart[2];

  const int t = threadIdx.x;
  const int s = blockIdx.x, b = blockIdx.y;
  const int vb = s * VC;
  const float* stb = state + (size_t)b * Ux * Wx;
  const float* inb = input + (size_t)b * Ux;

  // ======== Phase A: issue ALL global loads into registers ========
  float4 sx[2][4];
#pragma unroll
  for (int i = 0; i < 2; ++i) {
    const float4* src = reinterpret_cast<const float4*>(stb + i * 8192 + t * 16);
    sx[i][0] = src[0]; sx[i][1] = src[1]; sx[i][2] = src[2]; sx[i][3] = src[3];
  }
  float4 wx[2];
#pragma unroll
  for (int i = 0; i < 2; ++i) {
    int F = i * 512 + t;                 // float4 index over 128x32 w-chunk
    wx[i] = *reinterpret_cast<const float4*>(w + (F >> 3) * Ux + vb + (F & 7) * 4);
  }
  float inval = 0.f, dval = 0.f;
  if (t < Wx) {
    inval = inb[t];
    dval = (t < Wx - 1) ? stb[127 * Wx + t + 1] : inb[127];
  }
  float4 wdx = {};
  if (t < 8) wdx = *reinterpret_cast<const float4*>(w + 2 * Ux * Ux + vb + t * 4);

  // ======== Phase B: convert + LDS writes ========
#pragma unroll
  for (int i = 0; i < 2; ++i) {
    int g = i * 8192 + t * 16;           // flat f32 index, 16-aligned
    int j = g >> 7, k = g & 127;
    s16x8 p0 = { f2b(sx[i][0].x), f2b(sx[i][0].y), f2b(sx[i][0].z), f2b(sx[i][0].w),
                 f2b(sx[i][1].x), f2b(sx[i][1].y), f2b(sx[i][1].z), f2b(sx[i][1].w) };
    s16x8 p1 = { f2b(sx[i][2].x), f2b(sx[i][2].y), f2b(sx[i][2].z), f2b(sx[i][2].w),
                 f2b(sx[i][3].x), f2b(sx[i][3].y), f2b(sx[i][3].z), f2b(sx[i][3].w) };
    *reinterpret_cast<s16x8*>(&st_s[j][k])     = p0;
    *reinterpret_cast<s16x8*>(&st_s[j][k + 8]) = p1;
  }
#pragma unroll
  for (int i = 0; i < 2; ++i) {
    int F = i * 512 + t;
    int r = F >> 3, v4 = (F & 7) * 4;
    if (r < 127) {                       // shifted: wst[v][r+1] = w_hi[r][vb+v]
      wst[v4 + 0][r + 1] = f2b(wx[i].x);
      wst[v4 + 1][r + 1] = f2b(wx[i].y);
      wst[v4 + 2][r + 1] = f2b(wx[i].z);
      wst[v4 + 3][r + 1] = f2b(wx[i].w);
    } else {                             // row 127 kept in f32 for the epilogue
      w127_s[v4 + 0] = wx[i].x; w127_s[v4 + 1] = wx[i].y;
      w127_s[v4 + 2] = wx[i].z; w127_s[v4 + 3] = wx[i].w;
    }
  }
  if (t < Wx) st_s[t][128] = f2b(inval);
  if (t < VC) wst[t][0] = 0;
  if (t < 8) {
    wdot_s[t * 4 + 0] = wdx.x; wdot_s[t * 4 + 1] = wdx.y;
    wdot_s[t * 4 + 2] = wdx.z; wdot_s[t * 4 + 3] = wdx.w;
  }
  // exact fp32 dot[127] = ||flip_127||^2 (waves 0,1)
  if (t < Wx) {
    float p = dval * dval;
#pragma unroll
    for (int off = 32; off; off >>= 1) p += __shfl_down(p, off);
    if ((t & 63) == 0) dpart[t >> 6] = p;
  }
  __syncthreads();

  // ---- MFMA: wave wv owns j-tile rows wv*16..wv*16+15; 2 v-tiles + dot matvec.
  // A/B frag: row/col = l&15, k-contig 8 at (l>>4)*8; D: col=l&15, row=(l>>4)*4+r
  const int wv = t >> 6, l = t & 63, lc = l & 15, lg = l >> 4;
  fx4 aH0 = {}, aH1 = {}, aD = {};
#pragma unroll
  for (int kt = 0; kt < 4; ++kt) {
    const int ko = kt * 32 + lg * 8;
    s16x8 bd = *reinterpret_cast<const s16x8*>(&st_s[127][ko]);   // broadcast row 127
    s16x8 b0 = *reinterpret_cast<const s16x8*>(&wst[lc][ko]);
    s16x8 b1 = *reinterpret_cast<const s16x8*>(&wst[lc + 16][ko]);
    s16x8 a  = *reinterpret_cast<const s16x8*>(&st_s[wv * 16 + lc][ko]);
    aH0 = __builtin_amdgcn_mfma_f32_16x16x32_bf16(a, b0, aH0, 0, 0, 0);
    aH1 = __builtin_amdgcn_mfma_f32_16x16x32_bf16(a, b1, aH1, 0, 0, 0);
    aD  = __builtin_amdgcn_mfma_f32_16x16x32_bf16(a, bd, aD,  0, 0, 0);
  }

  // ---- epilogue in registers: shift corrections + dot*w_dot + input*w_hi[127]
  const float in127  = b2f(st_s[127][128]);
  const float st0127 = b2f(st_s[127][0]);
  const float d127   = dpart[0] + dpart[1];
  const float wd0 = wdot_s[lc], wd1 = wdot_s[lc + 16];
  const float w70 = w127_s[lc], w71 = w127_s[lc + 16];
  float sim0[4], sim1[4];
#pragma unroll
  for (int r = 0; r < 4; ++r) {
    const int row = wv * 16 + lg * 4 + r;
    float st0 = b2f(st_s[row][0]);
    float inr = b2f(st_s[row][128]);
    float dotv = aD[r] - st0 * st0127 + inr * in127;
    if (row == Wx - 1) dotv = d127;                 // exact fp32 diagonal
    sim0[r] = aH0[r] + dotv * wd0 + inr * w70;
    sim1[r] = aH1[r] + dotv * wd1 + inr * w71;
  }

  // ---- per-wave online softmax: local max m, local sum s, local weighted p
  float m0 = -3.4e38f, m1 = -3.4e38f;
#pragma unroll
  for (int r = 0; r < 4; ++r) { m0 = fmaxf(m0, sim0[r]); m1 = fmaxf(m1, sim1[r]); }
  m0 = fmaxf(m0, __shfl_xor(m0, 16)); m0 = fmaxf(m0, __shfl_xor(m0, 32));
  m1 = fmaxf(m1, __shfl_xor(m1, 16)); m1 = fmaxf(m1, __shfl_xor(m1, 32));
  float s0 = 0.f, s1 = 0.f, p0 = 0.f, p1 = 0.f;
#pragma unroll
  for (int r = 0; r < 4; ++r) {
    const int row = wv * 16 + lg * 4 + r;
    float e0 = __expf(sim0[r] - m0);
    float e1 = __expf(sim1[r] - m1);
    s0 += e0; s1 += e1;
    p0 = fmaf(b2f(st_s[row][vb + lc + 1]), e0, p0);    // flip[row][vb+lc]
    p1 = fmaf(b2f(st_s[row][vb + lc + 17]), e1, p1);   // flip[row][vb+lc+16] ([128]=input)
  }
  s0 += __shfl_xor(s0, 16); s0 += __shfl_xor(s0, 32);
  s1 += __shfl_xor(s1, 16); s1 += __shfl_xor(s1, 32);
  p0 += __shfl_xor(p0, 16); p0 += __shfl_xor(p0, 32);
  p1 += __shfl_xor(p1, 16); p1 += __shfl_xor(p1, 32);
  if (l < 16) {
    wm[wv][l] = m0;  wm[wv][16 + l] = m1;
    wsum[wv][l] = s0; wsum[wv][16 + l] = s1;
    wp[wv][l] = p0;  wp[wv][16 + l] = p1;
  }
  __syncthreads();

  // ---- ONE combine: wave 0 lanes 0..31, rescale partials by e^{m_wv - M}
  if (wv == 0 && l < VC) {
    float M = wm[0][l];
#pragma unroll
    for (int r = 1; r < 8; ++r) M = fmaxf(M, wm[r][l]);
    float S = 0.f, P = 0.f;
#pragma unroll
    for (int r = 0; r < 8; ++r) {
      float sc = __expf(wm[r][l] - M);
      S = fmaf(wsum[r][l], sc, S);
      P = fmaf(wp[r][l],  sc, P);
    }
    out[(size_t)b * Ux + vb + l] = P / S;
  }
}

extern "C" void kernel_launch(void* const* d_in, const int* in_sizes, int n_in,
                              void* d_out, int out_size, void* d_ws, size_t ws_size,
                              hipStream_t stream) {
  const float* input = (const float*)d_in[0];
  const float* state = (const float*)d_in[1];
  const float* w     = (const float*)d_in[2];
  // d_in[3] (bias) not needed: cancels in softmax over j.
  float* out = (float*)d_out;
  dim3 grid(NS, Bx);
  rsa_kernel<<<grid, dim3(512), 0, stream>>>(input, state, w, out);
}